// Round 2
// 704.313 us; speedup vs baseline: 2.1171x; 2.1171x over previous
//
#include <hip/hip_runtime.h>

#define BIGF 3.402823466e38f
#define LCAP 2048u
#define NB   2048   // grid for the big streaming kernels (8 blocks/CU on 256 CUs)
#define NT   256

// ---------------------------------------------------------------------------
// Workspace state. Harness poisons ws with 0xAA before each timed call, so
// k0_init re-initializes everything each launch.
// ---------------------------------------------------------------------------
struct State {
  double sum0, sumsq0;
  double sum1, sumsq1;
  double sum2, sumsq2;
  unsigned n0, n1, n2;
  float maxabs0, minnz0, maxnz0;
  float maxabs1, minnz1, maxnz1;
  float maxabs2, minnz2, maxnz2;
  float bmin0, bmax0;   // iter-0 inlier min/max
  float bmin1, bmax1;   // iter-1 band min/max
  unsigned count1, count2;
  float thr0f, thr1f;   // precomputed thresholds (k1r / k2r)
  int special0;         // thr0 > maxabs0 -> inliers = nonzero set
  float thr[10], delta[10], zp[10];
  int valid[10];
};

// ---------------------------------------------------------------------------
// Atomic float min/max via CAS — used ONLY by k3 (256 blocks, cheap).
// ---------------------------------------------------------------------------
__device__ inline void atomicMinF(float* addr, float v) {
  unsigned* ua = (unsigned*)addr;
  unsigned cur = *ua;
  while (v < __uint_as_float(cur)) {
    unsigned prev = atomicCAS(ua, cur, __float_as_uint(v));
    if (prev == cur) break;
    cur = prev;
  }
}
__device__ inline void atomicMaxF(float* addr, float v) {
  unsigned* ua = (unsigned*)addr;
  unsigned cur = *ua;
  while (v > __uint_as_float(cur)) {
    unsigned prev = atomicCAS(ua, cur, __float_as_uint(v));
    if (prev == cur) break;
    cur = prev;
  }
}

// ---------------------------------------------------------------------------
// 8-quantity accumulator (also the per-block partial record).
// ---------------------------------------------------------------------------
struct Acc8 {
  double sum, sumsq;
  unsigned cnt;
  float maxabs, minnz, maxnz, bmin, bmax;
};
__device__ inline void acc_init(Acc8& a) {
  a.sum = 0.0; a.sumsq = 0.0; a.cnt = 0u;
  a.maxabs = 0.0f;
  a.minnz = BIGF; a.maxnz = -BIGF;
  a.bmin = BIGF; a.bmax = -BIGF;
}
__device__ inline void acc_merge(Acc8& a, const Acc8& b) {
  a.sum += b.sum; a.sumsq += b.sumsq; a.cnt += b.cnt;
  a.maxabs = fmaxf(a.maxabs, b.maxabs);
  a.minnz = fminf(a.minnz, b.minnz); a.maxnz = fmaxf(a.maxnz, b.maxnz);
  a.bmin = fminf(a.bmin, b.bmin);   a.bmax = fmaxf(a.bmax, b.bmax);
}
__device__ inline void acc_wave_reduce(Acc8& a) {
  #pragma unroll
  for (int off = 32; off > 0; off >>= 1) {
    a.sum    += __shfl_down(a.sum, off);
    a.sumsq  += __shfl_down(a.sumsq, off);
    a.cnt    += __shfl_down(a.cnt, off);
    a.maxabs = fmaxf(a.maxabs, __shfl_down(a.maxabs, off));
    a.minnz  = fminf(a.minnz,  __shfl_down(a.minnz, off));
    a.maxnz  = fmaxf(a.maxnz,  __shfl_down(a.maxnz, off));
    a.bmin   = fminf(a.bmin,   __shfl_down(a.bmin, off));
    a.bmax   = fmaxf(a.bmax,   __shfl_down(a.bmax, off));
  }
}
template <int NWAVES>
__device__ inline bool acc_block_reduce(Acc8& a, Acc8* s_part) {
  __syncthreads();
  acc_wave_reduce(a);
  int tid = threadIdx.x;
  if ((tid & 63) == 0) s_part[tid >> 6] = a;
  __syncthreads();
  if (tid == 0) {
    #pragma unroll
    for (int w = 1; w < NWAVES; ++w) acc_merge(a, s_part[w]);
    return true;
  }
  return false;
}

// thr = mean + 3*sqrt(var), unbiased var over the masked (nonzero) set.
__device__ inline float compute_thr(double sum, double sumsq, unsigned n) {
  double nf = (double)(n > 0u ? n : 1u);
  double mean = sum / nf;
  double nm1 = nf - 1.0; if (nm1 < 1.0) nm1 = 1.0;
  double var = (sumsq - sum * sum / nf) / nm1;
  if (var < 0.0) var = 0.0;
  return (float)(mean + 3.0 * sqrt(var));
}

__device__ inline void finalize_group(float thr, float maxabs, unsigned n,
                                      float minnz, float maxnz, float bmin, float bmax,
                                      bool clampZero, float* dOut, float* zOut, int* vOut) {
  float xmin, xmax;
  if (thr > maxabs) { xmin = minnz; xmax = maxnz; }
  else {
    xmin = bmin; xmax = bmax;
    if (clampZero) { xmin = fminf(xmin, 0.0f); xmax = fmaxf(xmax, 0.0f); }
  }
  float d = (xmax - xmin) / 255.0f;
  int v = (n > 0u) ? 1 : 0;
  float z;
  if (v && d > 0.0f && d < BIGF) { z = rintf((-xmin) / d); }
  else { d = 1.0f; z = 0.0f; }
  *dOut = d; *zOut = z; *vOut = v;
}

// ---------------------------------------------------------------------------
// K0: init
// ---------------------------------------------------------------------------
__global__ void k0_init(State* st) {
  if (threadIdx.x == 0 && blockIdx.x == 0) {
    st->sum0 = 0.0; st->sumsq0 = 0.0; st->n0 = 0u;
    st->maxabs0 = 0.0f; st->minnz0 = BIGF; st->maxnz0 = -BIGF;
    st->sum1 = 0.0; st->sumsq1 = 0.0; st->n1 = 0u;
    st->maxabs1 = 0.0f; st->minnz1 = BIGF; st->maxnz1 = -BIGF;
    st->sum2 = 0.0; st->sumsq2 = 0.0; st->n2 = 0u;
    st->maxabs2 = 0.0f; st->minnz2 = BIGF; st->maxnz2 = -BIGF;
    st->bmin0 = BIGF; st->bmax0 = -BIGF;
    st->bmin1 = BIGF; st->bmax1 = -BIGF;
    st->count1 = 0u; st->count2 = 0u;
  }
}

// ---------------------------------------------------------------------------
// K1: full-array stats over x != 0 — branchless hot loop, 4 loads in flight,
// per-block partial to workspace (no global atomics).
// Zeros contribute exactly 0.0 to the fp64 sums, so sum/sumsq need no mask.
// ---------------------------------------------------------------------------
__device__ inline void stat1(float f, Acc8& a) {
  float ab = fabsf(f);
  bool nz = (f != 0.0f);
  a.cnt += nz ? 1u : 0u;
  double dab = (double)ab;
  a.sum += dab; a.sumsq += dab * dab;
  a.maxabs = fmaxf(a.maxabs, ab);
  a.minnz = fminf(a.minnz, nz ? f : BIGF);
  a.maxnz = fmaxf(a.maxnz, nz ? f : -BIGF);
}

__global__ void __launch_bounds__(256) k1_stats(const float* __restrict__ x, long long n,
                                                Acc8* __restrict__ part) {
  __shared__ Acc8 s_part[4];
  Acc8 a0, a1; acc_init(a0); acc_init(a1);
  const float4* x4 = (const float4*)x;
  long long n4 = n >> 2;
  long long tid = (long long)blockIdx.x * NT + threadIdx.x;
  long long nthreads = (long long)gridDim.x * NT;
  long long step = nthreads * 4;
  long long nfull = (n4 / step) * step;
  // main: block-contiguous 4x float4 (independent loads, branchless body)
  for (long long i = (long long)blockIdx.x * (NT * 4) + threadIdx.x; i < nfull; i += step) {
    float4 v0 = x4[i];
    float4 v1 = x4[i + NT];
    float4 v2 = x4[i + 2 * NT];
    float4 v3 = x4[i + 3 * NT];
    stat1(v0.x, a0); stat1(v0.y, a0); stat1(v0.z, a0); stat1(v0.w, a0);
    stat1(v1.x, a0); stat1(v1.y, a0); stat1(v1.z, a0); stat1(v1.w, a0);
    stat1(v2.x, a1); stat1(v2.y, a1); stat1(v2.z, a1); stat1(v2.w, a1);
    stat1(v3.x, a1); stat1(v3.y, a1); stat1(v3.z, a1); stat1(v3.w, a1);
  }
  // float4 tail
  for (long long i = nfull + tid; i < n4; i += nthreads) {
    float4 v = x4[i];
    stat1(v.x, a0); stat1(v.y, a0); stat1(v.z, a0); stat1(v.w, a0);
  }
  // scalar tail
  for (long long i = (n4 << 2) + tid; i < n; i += nthreads) stat1(x[i], a0);

  acc_merge(a0, a1);
  if (acc_block_reduce<4>(a0, s_part)) part[blockIdx.x] = a0;
}

// K1R: single block reduces the NB partials -> State; precompute thr0/special.
__global__ void __launch_bounds__(1024) k1r_reduce(State* st, const Acc8* __restrict__ part, int np) {
  __shared__ Acc8 s_part[16];
  Acc8 a; acc_init(a);
  for (int j = threadIdx.x; j < np; j += 1024) acc_merge(a, part[j]);
  if (acc_block_reduce<16>(a, s_part)) {
    st->sum0 = a.sum; st->sumsq0 = a.sumsq; st->n0 = a.cnt;
    st->maxabs0 = a.maxabs; st->minnz0 = a.minnz; st->maxnz0 = a.maxnz;
    float t = compute_thr(a.sum, a.sumsq, a.cnt);
    st->thr0f = t;
    st->special0 = (t > a.maxabs) ? 1 : 0;
  }
}

// ---------------------------------------------------------------------------
// K2: full pass with thr0: iter-0 inlier min/max, compact |x|>thr0, iter-1
// stats. Branchless stats; compaction via wave ballot + mbcnt prefix (one LDS
// atomic per wave-slot instead of one per outlier lane). Per-block partial to
// workspace; only the compaction flush touches a global atomic (1/block).
// ---------------------------------------------------------------------------
__device__ inline void proc2(float f, float thr0, bool special, Acc8& a,
                             unsigned* l_cnt, float* l_buf,
                             State* st, float* __restrict__ buf1, unsigned cap1) {
  float ab = fabsf(f);
  bool out = ab > thr0;
  bool inl = special ? (f != 0.0f) : (!out);
  a.bmin = fminf(a.bmin, inl ? f : BIGF);
  a.bmax = fmaxf(a.bmax, inl ? f : -BIGF);
  a.cnt += out ? 1u : 0u;
  double dab = out ? (double)ab : 0.0;
  a.sum += dab; a.sumsq += dab * dab;
  a.maxabs = fmaxf(a.maxabs, out ? ab : 0.0f);
  a.minnz = fminf(a.minnz, out ? f : BIGF);
  a.maxnz = fmaxf(a.maxnz, out ? f : -BIGF);
  // wave-aggregated compaction (m is wave-uniform -> uniform branch)
  unsigned long long m = __ballot(out);
  if (m) {
    unsigned lo = (unsigned)m, hi = (unsigned)(m >> 32);
    int pw = (int)__builtin_amdgcn_mbcnt_hi(hi, __builtin_amdgcn_mbcnt_lo(lo, 0u));
    int nout = __builtin_popcountll(m);
    int leader = __builtin_ctzll(m);
    unsigned bbase = 0u;
    if ((int)(threadIdx.x & 63) == leader) bbase = atomicAdd(l_cnt, (unsigned)nout);
    bbase = (unsigned)__shfl((int)bbase, leader);
    if (out) {
      unsigned p = bbase + (unsigned)pw;
      if (p < LCAP) l_buf[p] = f;
      else { unsigned g = atomicAdd(&st->count1, 1u); if (g < cap1) buf1[g] = f; }
    }
  }
}

__global__ void __launch_bounds__(256) k2_pass(const float* __restrict__ x, long long n, State* st,
                                               float* __restrict__ buf1, unsigned cap1,
                                               Acc8* __restrict__ part) {
  __shared__ Acc8 s_part[4];
  __shared__ float l_buf[LCAP];
  __shared__ unsigned l_cnt, l_base, l_m;
  if (threadIdx.x == 0) l_cnt = 0u;
  __syncthreads();

  float thr0 = st->thr0f;
  bool special = st->special0 != 0;

  Acc8 a0, a1; acc_init(a0); acc_init(a1);
  const float4* x4 = (const float4*)x;
  long long n4 = n >> 2;
  long long tid = (long long)blockIdx.x * NT + threadIdx.x;
  long long nthreads = (long long)gridDim.x * NT;
  long long step = nthreads * 4;
  long long nfull = (n4 / step) * step;
  for (long long i = (long long)blockIdx.x * (NT * 4) + threadIdx.x; i < nfull; i += step) {
    float4 v0 = x4[i];
    float4 v1 = x4[i + NT];
    float4 v2 = x4[i + 2 * NT];
    float4 v3 = x4[i + 3 * NT];
    proc2(v0.x, thr0, special, a0, &l_cnt, l_buf, st, buf1, cap1);
    proc2(v0.y, thr0, special, a0, &l_cnt, l_buf, st, buf1, cap1);
    proc2(v0.z, thr0, special, a0, &l_cnt, l_buf, st, buf1, cap1);
    proc2(v0.w, thr0, special, a0, &l_cnt, l_buf, st, buf1, cap1);
    proc2(v1.x, thr0, special, a0, &l_cnt, l_buf, st, buf1, cap1);
    proc2(v1.y, thr0, special, a0, &l_cnt, l_buf, st, buf1, cap1);
    proc2(v1.z, thr0, special, a0, &l_cnt, l_buf, st, buf1, cap1);
    proc2(v1.w, thr0, special, a0, &l_cnt, l_buf, st, buf1, cap1);
    proc2(v2.x, thr0, special, a1, &l_cnt, l_buf, st, buf1, cap1);
    proc2(v2.y, thr0, special, a1, &l_cnt, l_buf, st, buf1, cap1);
    proc2(v2.z, thr0, special, a1, &l_cnt, l_buf, st, buf1, cap1);
    proc2(v2.w, thr0, special, a1, &l_cnt, l_buf, st, buf1, cap1);
    proc2(v3.x, thr0, special, a1, &l_cnt, l_buf, st, buf1, cap1);
    proc2(v3.y, thr0, special, a1, &l_cnt, l_buf, st, buf1, cap1);
    proc2(v3.z, thr0, special, a1, &l_cnt, l_buf, st, buf1, cap1);
    proc2(v3.w, thr0, special, a1, &l_cnt, l_buf, st, buf1, cap1);
  }
  for (long long i = nfull + tid; i < n4; i += nthreads) {
    float4 v = x4[i];
    proc2(v.x, thr0, special, a0, &l_cnt, l_buf, st, buf1, cap1);
    proc2(v.y, thr0, special, a0, &l_cnt, l_buf, st, buf1, cap1);
    proc2(v.z, thr0, special, a0, &l_cnt, l_buf, st, buf1, cap1);
    proc2(v.w, thr0, special, a0, &l_cnt, l_buf, st, buf1, cap1);
  }
  for (long long i = (n4 << 2) + tid; i < n; i += nthreads) {
    proc2(x[i], thr0, special, a0, &l_cnt, l_buf, st, buf1, cap1);
  }

  // flush LDS-staged compaction with one global atomic per block
  __syncthreads();
  if (threadIdx.x == 0) {
    l_m = l_cnt < LCAP ? l_cnt : LCAP;
    l_base = atomicAdd(&st->count1, l_m);
  }
  __syncthreads();
  for (unsigned i = threadIdx.x; i < l_m; i += NT) {
    unsigned g = l_base + i;
    if (g < cap1) buf1[g] = l_buf[i];
  }
  acc_merge(a0, a1);
  if (acc_block_reduce<4>(a0, s_part)) part[blockIdx.x] = a0;
}

// K2R: reduce NB partials -> iter-0 band minmax + iter-1 stats; precompute thr1.
__global__ void __launch_bounds__(1024) k2r_reduce(State* st, const Acc8* __restrict__ part, int np) {
  __shared__ Acc8 s_part[16];
  Acc8 a; acc_init(a);
  for (int j = threadIdx.x; j < np; j += 1024) acc_merge(a, part[j]);
  if (acc_block_reduce<16>(a, s_part)) {
    st->bmin0 = a.bmin; st->bmax0 = a.bmax;
    st->sum1 = a.sum; st->sumsq1 = a.sumsq; st->n1 = a.cnt;
    st->maxabs1 = a.maxabs; st->minnz1 = a.minnz; st->maxnz1 = a.maxnz;
    st->thr1f = compute_thr(a.sum, a.sumsq, a.cnt);
  }
}

// ---------------------------------------------------------------------------
// K3: over compacted buf1 (~600K): iter-1 band min/max, compact |x|>thr1,
// iter-2 stats. Small — keep atomic epilogue (256 blocks only).
// ---------------------------------------------------------------------------
__global__ void __launch_bounds__(256) k3_pass(State* st, const float* __restrict__ buf1, unsigned cap1,
                                               float* __restrict__ buf2, unsigned cap2) {
  __shared__ Acc8 s_part[4];
  __shared__ float l_buf[LCAP];
  __shared__ unsigned l_cnt, l_base, l_m;
  if (threadIdx.x == 0) l_cnt = 0u;
  __syncthreads();

  unsigned c1 = st->count1; if (c1 > cap1) c1 = cap1;
  float thr1 = st->thr1f;

  Acc8 a; acc_init(a);
  unsigned stride = gridDim.x * blockDim.x;
  for (unsigned j = blockIdx.x * blockDim.x + threadIdx.x; j < c1; j += stride) {
    float f = buf1[j];
    float ab = fabsf(f);
    if (ab <= thr1) { a.bmin = fminf(a.bmin, f); a.bmax = fmaxf(a.bmax, f); }
    else {
      a.cnt++; a.sum += (double)ab; a.sumsq += (double)ab * (double)ab;
      a.maxabs = fmaxf(a.maxabs, ab);
      a.minnz = fminf(a.minnz, f); a.maxnz = fmaxf(a.maxnz, f);
      unsigned p = atomicAdd(&l_cnt, 1u);
      if (p < LCAP) l_buf[p] = f;
      else { unsigned g = atomicAdd(&st->count2, 1u); if (g < cap2) buf2[g] = f; }
    }
  }
  __syncthreads();
  if (threadIdx.x == 0) {
    l_m = l_cnt < LCAP ? l_cnt : LCAP;
    l_base = atomicAdd(&st->count2, l_m);
  }
  __syncthreads();
  for (unsigned i = threadIdx.x; i < l_m; i += blockDim.x) {
    unsigned g = l_base + i;
    if (g < cap2) buf2[g] = l_buf[i];
  }
  if (acc_block_reduce<4>(a, s_part)) {
    atomicMinF(&st->bmin1, a.bmin); atomicMaxF(&st->bmax1, a.bmax);
    atomicAdd(&st->sum2, a.sum); atomicAdd(&st->sumsq2, a.sumsq); atomicAdd(&st->n2, a.cnt);
    atomicMaxF(&st->maxabs2, a.maxabs);
    atomicMinF(&st->minnz2, a.minnz); atomicMaxF(&st->maxnz2, a.maxnz);
  }
}

// ---------------------------------------------------------------------------
// K4: single block. Finalize groups 0,1; iterations 2..9 over buf2 (~7K).
// ---------------------------------------------------------------------------
__global__ void __launch_bounds__(1024) k4_finalize(State* st, const float* __restrict__ buf2, unsigned cap2) {
  __shared__ Acc8 s_part[16];
  __shared__ float sh_thr[10], sh_delta[10], sh_zp[10];
  __shared__ int sh_valid[10];
  __shared__ double sh_sum, sh_sumsq;
  __shared__ unsigned sh_n;
  __shared__ float sh_maxabs, sh_minnz, sh_maxnz;
  int tid = threadIdx.x;

  if (tid == 0) {
    float thr0 = compute_thr(st->sum0, st->sumsq0, st->n0);
    sh_thr[0] = thr0;
    finalize_group(thr0, st->maxabs0, st->n0, st->minnz0, st->maxnz0,
                   st->bmin0, st->bmax0, /*clampZero=*/false,
                   &sh_delta[0], &sh_zp[0], &sh_valid[0]);
    float thr1 = compute_thr(st->sum1, st->sumsq1, st->n1);
    sh_thr[1] = thr1;
    finalize_group(thr1, st->maxabs1, st->n1, st->minnz1, st->maxnz1,
                   st->bmin1, st->bmax1, /*clampZero=*/true,
                   &sh_delta[1], &sh_zp[1], &sh_valid[1]);
    sh_sum = st->sum2; sh_sumsq = st->sumsq2; sh_n = st->n2;
    sh_maxabs = st->maxabs2; sh_minnz = st->minnz2; sh_maxnz = st->maxnz2;
  }
  __syncthreads();
  unsigned c2 = st->count2; if (c2 > cap2) c2 = cap2;

  for (int i = 2; i < 10; ++i) {
    if (tid == 0) sh_thr[i] = compute_thr(sh_sum, sh_sumsq, sh_n);
    __syncthreads();
    float tp = sh_thr[i - 1], tc = sh_thr[i];
    Acc8 a; acc_init(a);
    for (unsigned j = tid; j < c2; j += 1024u) {
      float f = buf2[j];
      float ab = fabsf(f);
      if (ab > tp && ab <= tc) { a.bmin = fminf(a.bmin, f); a.bmax = fmaxf(a.bmax, f); }
      if (ab > tc) {
        a.cnt++; a.sum += (double)ab; a.sumsq += (double)ab * (double)ab;
        a.maxabs = fmaxf(a.maxabs, ab);
        a.minnz = fminf(a.minnz, f); a.maxnz = fmaxf(a.maxnz, f);
      }
    }
    if (acc_block_reduce<16>(a, s_part)) {
      finalize_group(tc, sh_maxabs, sh_n, sh_minnz, sh_maxnz, a.bmin, a.bmax,
                     /*clampZero=*/true, &sh_delta[i], &sh_zp[i], &sh_valid[i]);
      if (sh_n > 0u) {  // done-propagation: keep zeros once dead
        sh_sum = a.sum; sh_sumsq = a.sumsq; sh_n = a.cnt;
        sh_maxabs = a.maxabs; sh_minnz = a.minnz; sh_maxnz = a.maxnz;
      }
    }
    __syncthreads();
  }
  if (tid < 10) {
    st->thr[tid] = sh_thr[tid]; st->delta[tid] = sh_delta[tid];
    st->zp[tid] = sh_zp[tid];   st->valid[tid] = sh_valid[tid];
  }
}

// ---------------------------------------------------------------------------
// K5: dequant. Numerics identical to the passing version; loop restructured
// for 4 independent float4 loads/stores per iteration.
// ---------------------------------------------------------------------------
__device__ inline float dq1(float v, const float* thr, const float* dl, const float* zp, const int* vld) {
  float ab = fabsf(v);
  float d = dl[0], z = zp[0];
  #pragma unroll
  for (int i = 1; i < 10; ++i) {
    bool band = (vld[i] != 0) && (ab > thr[i - 1]) && (ab <= thr[i]);
    d = band ? dl[i] : d;
    z = band ? zp[i] : z;
  }
  float q = rintf(v / d) + z;            // IEEE divide + half-even round, matches jnp
  q = fminf(fmaxf(q, 0.0f), 255.0f);
  return (q - z) * d;
}
__device__ inline float4 dq4(float4 v, const float* thr, const float* dl, const float* zp, const int* vld) {
  float4 o;
  o.x = dq1(v.x, thr, dl, zp, vld);
  o.y = dq1(v.y, thr, dl, zp, vld);
  o.z = dq1(v.z, thr, dl, zp, vld);
  o.w = dq1(v.w, thr, dl, zp, vld);
  return o;
}

__global__ void __launch_bounds__(256) k5_dequant(const float* __restrict__ x, float* __restrict__ out,
                                                  long long n, const State* __restrict__ st) {
  float thr[10], dl[10], zp[10]; int vld[10];
  #pragma unroll
  for (int i = 0; i < 10; ++i) {
    thr[i] = st->thr[i]; dl[i] = st->delta[i]; zp[i] = st->zp[i]; vld[i] = st->valid[i];
  }
  const float4* x4 = (const float4*)x;
  float4* o4 = (float4*)out;
  long long n4 = n >> 2;
  long long tid = (long long)blockIdx.x * NT + threadIdx.x;
  long long nthreads = (long long)gridDim.x * NT;
  long long step = nthreads * 4;
  long long nfull = (n4 / step) * step;
  for (long long i = (long long)blockIdx.x * (NT * 4) + threadIdx.x; i < nfull; i += step) {
    float4 v0 = x4[i];
    float4 v1 = x4[i + NT];
    float4 v2 = x4[i + 2 * NT];
    float4 v3 = x4[i + 3 * NT];
    o4[i]          = dq4(v0, thr, dl, zp, vld);
    o4[i + NT]     = dq4(v1, thr, dl, zp, vld);
    o4[i + 2 * NT] = dq4(v2, thr, dl, zp, vld);
    o4[i + 3 * NT] = dq4(v3, thr, dl, zp, vld);
  }
  for (long long i = nfull + tid; i < n4; i += nthreads) {
    o4[i] = dq4(x4[i], thr, dl, zp, vld);
  }
  for (long long i = (n4 << 2) + tid; i < n; i += nthreads) {
    out[i] = dq1(x[i], thr, dl, zp, vld);
  }
}

// ---------------------------------------------------------------------------
extern "C" void kernel_launch(void* const* d_in, const int* in_sizes, int n_in,
                              void* d_out, int out_size, void* d_ws, size_t ws_size,
                              hipStream_t stream) {
  const float* x = (const float*)d_in[0];
  float* out = (float*)d_out;
  long long n = (long long)in_sizes[0];

  // ws carve: State | partials1 | partials2 | buf2 | buf1
  char* p = (char*)d_ws;
  State* st = (State*)p;            p += 4096;
  Acc8* part1 = (Acc8*)p;           p += (size_t)NB * sizeof(Acc8);
  Acc8* part2 = (Acc8*)p;           p += (size_t)NB * sizeof(Acc8);
  size_t used = (size_t)(p - (char*)d_ws);
  used = (used + 255) & ~(size_t)255;
  size_t avail = ws_size > used ? ws_size - used : 0;
  size_t cap2_sz = avail / 8;
  if (cap2_sz > (size_t)(1u << 20) * 4) cap2_sz = (size_t)(1u << 20) * 4;
  unsigned cap2 = (unsigned)(cap2_sz / 4);
  float* buf2 = (float*)((char*)d_ws + used);
  float* buf1 = buf2 + cap2;
  unsigned cap1 = (unsigned)((avail - (size_t)cap2 * 4) / 4);

  hipLaunchKernelGGL(k0_init,     dim3(1),   dim3(64),   0, stream, st);
  hipLaunchKernelGGL(k1_stats,    dim3(NB),  dim3(NT),   0, stream, x, n, part1);
  hipLaunchKernelGGL(k1r_reduce,  dim3(1),   dim3(1024), 0, stream, st, (const Acc8*)part1, NB);
  hipLaunchKernelGGL(k2_pass,     dim3(NB),  dim3(NT),   0, stream, x, n, st, buf1, cap1, part2);
  hipLaunchKernelGGL(k2r_reduce,  dim3(1),   dim3(1024), 0, stream, st, (const Acc8*)part2, NB);
  hipLaunchKernelGGL(k3_pass,     dim3(256), dim3(NT),   0, stream, st, buf1, cap1, buf2, cap2);
  hipLaunchKernelGGL(k4_finalize, dim3(1),   dim3(1024), 0, stream, st, buf2, cap2);
  hipLaunchKernelGGL(k5_dequant,  dim3(NB),  dim3(NT),   0, stream, x, out, n, st);
}

// Round 3
// 676.580 us; speedup vs baseline: 2.2039x; 1.0410x over previous
//
#include <hip/hip_runtime.h>

#define BIGF 3.402823466e38f
#define LCAP 2048u
#define NB   2048   // grid for the big streaming kernels (8 blocks/CU on 256 CUs)
#define NT   256

typedef float f32x4 __attribute__((ext_vector_type(4)));

// ---------------------------------------------------------------------------
// Workspace state. Harness poisons ws with 0xAA before each timed call; k1r
// re-initializes every field each launch (k0 was folded into k1r).
// ---------------------------------------------------------------------------
struct State {
  double sum0, sumsq0;
  double sum1, sumsq1;
  double sum2, sumsq2;
  unsigned n0, n1, n2;
  float maxabs0, minnz0, maxnz0;
  float maxabs1, minnz1, maxnz1;
  float maxabs2, minnz2, maxnz2;
  float bmin0, bmax0;   // iter-0 inlier min/max
  float bmin1, bmax1;   // iter-1 band min/max
  unsigned count1, count2;
  float thr0f, thr1f;   // precomputed thresholds (k1r / k2r)
  int special0;         // thr0 > maxabs0 -> inliers = nonzero set
  float thr[10], delta[10], zp[10];
  int valid[10];
};

// ---------------------------------------------------------------------------
// Atomic float min/max via CAS — used ONLY by k3 (256 blocks, cheap).
// ---------------------------------------------------------------------------
__device__ inline void atomicMinF(float* addr, float v) {
  unsigned* ua = (unsigned*)addr;
  unsigned cur = *ua;
  while (v < __uint_as_float(cur)) {
    unsigned prev = atomicCAS(ua, cur, __float_as_uint(v));
    if (prev == cur) break;
    cur = prev;
  }
}
__device__ inline void atomicMaxF(float* addr, float v) {
  unsigned* ua = (unsigned*)addr;
  unsigned cur = *ua;
  while (v > __uint_as_float(cur)) {
    unsigned prev = atomicCAS(ua, cur, __float_as_uint(v));
    if (prev == cur) break;
    cur = prev;
  }
}

// ---------------------------------------------------------------------------
// 8-quantity accumulator (also the per-block partial record).
// ---------------------------------------------------------------------------
struct Acc8 {
  double sum, sumsq;
  unsigned cnt;
  float maxabs, minnz, maxnz, bmin, bmax;
};
__device__ inline void acc_init(Acc8& a) {
  a.sum = 0.0; a.sumsq = 0.0; a.cnt = 0u;
  a.maxabs = 0.0f;
  a.minnz = BIGF; a.maxnz = -BIGF;
  a.bmin = BIGF; a.bmax = -BIGF;
}
__device__ inline void acc_merge(Acc8& a, const Acc8& b) {
  a.sum += b.sum; a.sumsq += b.sumsq; a.cnt += b.cnt;
  a.maxabs = fmaxf(a.maxabs, b.maxabs);
  a.minnz = fminf(a.minnz, b.minnz); a.maxnz = fmaxf(a.maxnz, b.maxnz);
  a.bmin = fminf(a.bmin, b.bmin);   a.bmax = fmaxf(a.bmax, b.bmax);
}
__device__ inline void acc_wave_reduce(Acc8& a) {
  #pragma unroll
  for (int off = 32; off > 0; off >>= 1) {
    a.sum    += __shfl_down(a.sum, off);
    a.sumsq  += __shfl_down(a.sumsq, off);
    a.cnt    += __shfl_down(a.cnt, off);
    a.maxabs = fmaxf(a.maxabs, __shfl_down(a.maxabs, off));
    a.minnz  = fminf(a.minnz,  __shfl_down(a.minnz, off));
    a.maxnz  = fmaxf(a.maxnz,  __shfl_down(a.maxnz, off));
    a.bmin   = fminf(a.bmin,   __shfl_down(a.bmin, off));
    a.bmax   = fmaxf(a.bmax,   __shfl_down(a.bmax, off));
  }
}
template <int NWAVES>
__device__ inline bool acc_block_reduce(Acc8& a, Acc8* s_part) {
  __syncthreads();
  acc_wave_reduce(a);
  int tid = threadIdx.x;
  if ((tid & 63) == 0) s_part[tid >> 6] = a;
  __syncthreads();
  if (tid == 0) {
    #pragma unroll
    for (int w = 1; w < NWAVES; ++w) acc_merge(a, s_part[w]);
    return true;
  }
  return false;
}

// thr = mean + 3*sqrt(var), unbiased var over the masked (nonzero) set.
__device__ inline float compute_thr(double sum, double sumsq, unsigned n) {
  double nf = (double)(n > 0u ? n : 1u);
  double mean = sum / nf;
  double nm1 = nf - 1.0; if (nm1 < 1.0) nm1 = 1.0;
  double var = (sumsq - sum * sum / nf) / nm1;
  if (var < 0.0) var = 0.0;
  return (float)(mean + 3.0 * sqrt(var));
}

__device__ inline void finalize_group(float thr, float maxabs, unsigned n,
                                      float minnz, float maxnz, float bmin, float bmax,
                                      bool clampZero, float* dOut, float* zOut, int* vOut) {
  float xmin, xmax;
  if (thr > maxabs) { xmin = minnz; xmax = maxnz; }
  else {
    xmin = bmin; xmax = bmax;
    if (clampZero) { xmin = fminf(xmin, 0.0f); xmax = fmaxf(xmax, 0.0f); }
  }
  float d = (xmax - xmin) / 255.0f;
  int v = (n > 0u) ? 1 : 0;
  float z;
  if (v && d > 0.0f && d < BIGF) { z = rintf((-xmin) / d); }
  else { d = 1.0f; z = 0.0f; }
  *dOut = d; *zOut = z; *vOut = v;
}

// ---------------------------------------------------------------------------
// K1: full-array stats over x != 0 — branchless, 8 loads in flight, 4
// interleaved accumulators (halve the fp64 dependence chain), per-block
// partial to workspace (no global atomics).
// ---------------------------------------------------------------------------
__device__ inline void stat1(float f, Acc8& a) {
  float ab = fabsf(f);
  bool nz = (f != 0.0f);
  a.cnt += nz ? 1u : 0u;
  double dab = (double)ab;
  a.sum += dab; a.sumsq += dab * dab;
  a.maxabs = fmaxf(a.maxabs, ab);
  a.minnz = fminf(a.minnz, nz ? f : BIGF);
  a.maxnz = fmaxf(a.maxnz, nz ? f : -BIGF);
}

__global__ void __launch_bounds__(256) k1_stats(const float* __restrict__ x, long long n,
                                                Acc8* __restrict__ part) {
  __shared__ Acc8 s_part[4];
  Acc8 a[4];
  #pragma unroll
  for (int u = 0; u < 4; ++u) acc_init(a[u]);
  const f32x4* x4 = (const f32x4*)x;
  long long n4 = n >> 2;
  long long tid = (long long)blockIdx.x * NT + threadIdx.x;
  long long nthreads = (long long)gridDim.x * NT;
  long long step = nthreads * 8;
  long long nfull = (n4 / step) * step;
  for (long long i = (long long)blockIdx.x * (NT * 8) + threadIdx.x; i < nfull; i += step) {
    f32x4 v[8];
    #pragma unroll
    for (int u = 0; u < 8; ++u) v[u] = x4[i + u * NT];
    #pragma unroll
    for (int u = 0; u < 8; ++u) {
      stat1(v[u].x, a[u & 3]); stat1(v[u].y, a[u & 3]);
      stat1(v[u].z, a[u & 3]); stat1(v[u].w, a[u & 3]);
    }
  }
  for (long long i = nfull + tid; i < n4; i += nthreads) {
    f32x4 v = x4[i];
    stat1(v.x, a[0]); stat1(v.y, a[0]); stat1(v.z, a[0]); stat1(v.w, a[0]);
  }
  for (long long i = (n4 << 2) + tid; i < n; i += nthreads) stat1(x[i], a[0]);

  acc_merge(a[0], a[1]); acc_merge(a[2], a[3]); acc_merge(a[0], a[2]);
  if (acc_block_reduce<4>(a[0], s_part)) part[blockIdx.x] = a[0];
}

// K1R: single block reduces the NB partials -> State. Also does ALL State
// init (k0 folded in) and precomputes thr0/special.
__global__ void __launch_bounds__(1024) k1r_reduce(State* st, const Acc8* __restrict__ part, int np) {
  __shared__ Acc8 s_part[16];
  Acc8 a; acc_init(a);
  for (int j = threadIdx.x; j < np; j += 1024) acc_merge(a, part[j]);
  if (acc_block_reduce<16>(a, s_part)) {
    st->sum0 = a.sum; st->sumsq0 = a.sumsq; st->n0 = a.cnt;
    st->maxabs0 = a.maxabs; st->minnz0 = a.minnz; st->maxnz0 = a.maxnz;
    float t = compute_thr(a.sum, a.sumsq, a.cnt);
    st->thr0f = t;
    st->special0 = (t > a.maxabs) ? 1 : 0;
    // init for k2/k3/k4 (workspace is poisoned each launch):
    st->count1 = 0u; st->count2 = 0u;
    st->bmin1 = BIGF; st->bmax1 = -BIGF;
    st->sum2 = 0.0; st->sumsq2 = 0.0; st->n2 = 0u;
    // max|x| over any outlier band == global max|x| whenever band non-empty
    st->maxabs2 = a.maxabs; st->minnz2 = BIGF; st->maxnz2 = -BIGF;
  }
}

// ---------------------------------------------------------------------------
// K2: full pass with thr0: iter-0 inlier min/max, compact (value,index) pairs
// of |x|>thr0, iter-1 stats (maxabs dropped: == maxabs0 when non-empty).
// Wave-ballot-aggregated compaction; per-block partial to workspace.
// ---------------------------------------------------------------------------
__device__ inline void proc2(float f, unsigned idx, float thr0, bool special, Acc8& a,
                             unsigned* l_cnt, float2* l_buf,
                             State* st, float2* __restrict__ buf1, unsigned cap1) {
  float ab = fabsf(f);
  bool out = ab > thr0;
  bool inl = special ? (f != 0.0f) : (!out);
  a.bmin = fminf(a.bmin, inl ? f : BIGF);
  a.bmax = fmaxf(a.bmax, inl ? f : -BIGF);
  a.cnt += out ? 1u : 0u;
  double dab = out ? (double)ab : 0.0;
  a.sum += dab; a.sumsq += dab * dab;
  a.minnz = fminf(a.minnz, out ? f : BIGF);
  a.maxnz = fmaxf(a.maxnz, out ? f : -BIGF);
  // wave-aggregated compaction (m is wave-uniform -> uniform branch)
  unsigned long long m = __ballot(out);
  if (m) {
    unsigned lo = (unsigned)m, hi = (unsigned)(m >> 32);
    int pw = (int)__builtin_amdgcn_mbcnt_hi(hi, __builtin_amdgcn_mbcnt_lo(lo, 0u));
    int nout = __builtin_popcountll(m);
    int leader = __builtin_ctzll(m);
    unsigned bbase = 0u;
    if ((int)(threadIdx.x & 63) == leader) bbase = atomicAdd(l_cnt, (unsigned)nout);
    bbase = (unsigned)__shfl((int)bbase, leader);
    if (out) {
      unsigned p = bbase + (unsigned)pw;
      float2 rec = make_float2(f, __uint_as_float(idx));
      if (p < LCAP) l_buf[p] = rec;
      else { unsigned g = atomicAdd(&st->count1, 1u); if (g < cap1) buf1[g] = rec; }
    }
  }
}

__global__ void __launch_bounds__(256) k2_pass(const float* __restrict__ x, long long n, State* st,
                                               float2* __restrict__ buf1, unsigned cap1,
                                               Acc8* __restrict__ part) {
  __shared__ Acc8 s_part[4];
  __shared__ float2 l_buf[LCAP];
  __shared__ unsigned l_cnt, l_base, l_m;
  if (threadIdx.x == 0) l_cnt = 0u;
  __syncthreads();

  float thr0 = st->thr0f;
  bool special = st->special0 != 0;

  Acc8 a0, a1; acc_init(a0); acc_init(a1);
  const f32x4* x4 = (const f32x4*)x;
  long long n4 = n >> 2;
  long long tid = (long long)blockIdx.x * NT + threadIdx.x;
  long long nthreads = (long long)gridDim.x * NT;
  long long step = nthreads * 4;
  long long nfull = (n4 / step) * step;
  for (long long i = (long long)blockIdx.x * (NT * 4) + threadIdx.x; i < nfull; i += step) {
    f32x4 v0 = x4[i];
    f32x4 v1 = x4[i + NT];
    f32x4 v2 = x4[i + 2 * NT];
    f32x4 v3 = x4[i + 3 * NT];
    unsigned b0 = (unsigned)(i) << 2, b1 = (unsigned)(i + NT) << 2,
             b2 = (unsigned)(i + 2 * NT) << 2, b3 = (unsigned)(i + 3 * NT) << 2;
    proc2(v0.x, b0 + 0u, thr0, special, a0, &l_cnt, l_buf, st, buf1, cap1);
    proc2(v0.y, b0 + 1u, thr0, special, a0, &l_cnt, l_buf, st, buf1, cap1);
    proc2(v0.z, b0 + 2u, thr0, special, a0, &l_cnt, l_buf, st, buf1, cap1);
    proc2(v0.w, b0 + 3u, thr0, special, a0, &l_cnt, l_buf, st, buf1, cap1);
    proc2(v1.x, b1 + 0u, thr0, special, a0, &l_cnt, l_buf, st, buf1, cap1);
    proc2(v1.y, b1 + 1u, thr0, special, a0, &l_cnt, l_buf, st, buf1, cap1);
    proc2(v1.z, b1 + 2u, thr0, special, a0, &l_cnt, l_buf, st, buf1, cap1);
    proc2(v1.w, b1 + 3u, thr0, special, a0, &l_cnt, l_buf, st, buf1, cap1);
    proc2(v2.x, b2 + 0u, thr0, special, a1, &l_cnt, l_buf, st, buf1, cap1);
    proc2(v2.y, b2 + 1u, thr0, special, a1, &l_cnt, l_buf, st, buf1, cap1);
    proc2(v2.z, b2 + 2u, thr0, special, a1, &l_cnt, l_buf, st, buf1, cap1);
    proc2(v2.w, b2 + 3u, thr0, special, a1, &l_cnt, l_buf, st, buf1, cap1);
    proc2(v3.x, b3 + 0u, thr0, special, a1, &l_cnt, l_buf, st, buf1, cap1);
    proc2(v3.y, b3 + 1u, thr0, special, a1, &l_cnt, l_buf, st, buf1, cap1);
    proc2(v3.z, b3 + 2u, thr0, special, a1, &l_cnt, l_buf, st, buf1, cap1);
    proc2(v3.w, b3 + 3u, thr0, special, a1, &l_cnt, l_buf, st, buf1, cap1);
  }
  for (long long i = nfull + tid; i < n4; i += nthreads) {
    f32x4 v = x4[i];
    unsigned b = (unsigned)(i) << 2;
    proc2(v.x, b + 0u, thr0, special, a0, &l_cnt, l_buf, st, buf1, cap1);
    proc2(v.y, b + 1u, thr0, special, a0, &l_cnt, l_buf, st, buf1, cap1);
    proc2(v.z, b + 2u, thr0, special, a0, &l_cnt, l_buf, st, buf1, cap1);
    proc2(v.w, b + 3u, thr0, special, a0, &l_cnt, l_buf, st, buf1, cap1);
  }
  for (long long i = (n4 << 2) + tid; i < n; i += nthreads) {
    proc2(x[i], (unsigned)i, thr0, special, a0, &l_cnt, l_buf, st, buf1, cap1);
  }

  // flush LDS-staged compaction with one global atomic per block
  __syncthreads();
  if (threadIdx.x == 0) {
    l_m = l_cnt < LCAP ? l_cnt : LCAP;
    l_base = atomicAdd(&st->count1, l_m);
  }
  __syncthreads();
  for (unsigned i = threadIdx.x; i < l_m; i += NT) {
    unsigned g = l_base + i;
    if (g < cap1) buf1[g] = l_buf[i];
  }
  acc_merge(a0, a1);
  if (acc_block_reduce<4>(a0, s_part)) part[blockIdx.x] = a0;
}

// K2R: reduce NB partials -> iter-0 band minmax + iter-1 stats; thr1.
__global__ void __launch_bounds__(1024) k2r_reduce(State* st, const Acc8* __restrict__ part, int np) {
  __shared__ Acc8 s_part[16];
  Acc8 a; acc_init(a);
  for (int j = threadIdx.x; j < np; j += 1024) acc_merge(a, part[j]);
  if (acc_block_reduce<16>(a, s_part)) {
    st->bmin0 = a.bmin; st->bmax0 = a.bmax;
    st->sum1 = a.sum; st->sumsq1 = a.sumsq; st->n1 = a.cnt;
    st->maxabs1 = st->maxabs0;  // == maxabs0 whenever n1 > 0
    st->minnz1 = a.minnz; st->maxnz1 = a.maxnz;
    st->thr1f = compute_thr(a.sum, a.sumsq, a.cnt);
  }
}

// ---------------------------------------------------------------------------
// K3: over compacted buf1 pairs (~600K): iter-1 band min/max, compact values
// of |x|>thr1 to buf2, iter-2 stats. Small — atomic epilogue fine.
// ---------------------------------------------------------------------------
__global__ void __launch_bounds__(256) k3_pass(State* st, const float2* __restrict__ buf1, unsigned cap1,
                                               float* __restrict__ buf2, unsigned cap2) {
  __shared__ Acc8 s_part[4];
  __shared__ float l_buf[LCAP];
  __shared__ unsigned l_cnt, l_base, l_m;
  if (threadIdx.x == 0) l_cnt = 0u;
  __syncthreads();

  unsigned c1 = st->count1; if (c1 > cap1) c1 = cap1;
  float thr1 = st->thr1f;

  Acc8 a; acc_init(a);
  unsigned stride = gridDim.x * blockDim.x;
  for (unsigned j = blockIdx.x * blockDim.x + threadIdx.x; j < c1; j += stride) {
    float f = buf1[j].x;
    float ab = fabsf(f);
    if (ab <= thr1) { a.bmin = fminf(a.bmin, f); a.bmax = fmaxf(a.bmax, f); }
    else {
      a.cnt++; a.sum += (double)ab; a.sumsq += (double)ab * (double)ab;
      a.minnz = fminf(a.minnz, f); a.maxnz = fmaxf(a.maxnz, f);
      unsigned p = atomicAdd(&l_cnt, 1u);
      if (p < LCAP) l_buf[p] = f;
      else { unsigned g = atomicAdd(&st->count2, 1u); if (g < cap2) buf2[g] = f; }
    }
  }
  __syncthreads();
  if (threadIdx.x == 0) {
    l_m = l_cnt < LCAP ? l_cnt : LCAP;
    l_base = atomicAdd(&st->count2, l_m);
  }
  __syncthreads();
  for (unsigned i = threadIdx.x; i < l_m; i += blockDim.x) {
    unsigned g = l_base + i;
    if (g < cap2) buf2[g] = l_buf[i];
  }
  if (acc_block_reduce<4>(a, s_part)) {
    atomicMinF(&st->bmin1, a.bmin); atomicMaxF(&st->bmax1, a.bmax);
    atomicAdd(&st->sum2, a.sum); atomicAdd(&st->sumsq2, a.sumsq); atomicAdd(&st->n2, a.cnt);
    atomicMinF(&st->minnz2, a.minnz); atomicMaxF(&st->maxnz2, a.maxnz);
  }
}

// ---------------------------------------------------------------------------
// K4: single block. Finalize groups 0,1; iterations 2..9 over buf2 (~7K).
// ---------------------------------------------------------------------------
__global__ void __launch_bounds__(1024) k4_finalize(State* st, const float* __restrict__ buf2, unsigned cap2) {
  __shared__ Acc8 s_part[16];
  __shared__ float sh_thr[10], sh_delta[10], sh_zp[10];
  __shared__ int sh_valid[10];
  __shared__ double sh_sum, sh_sumsq;
  __shared__ unsigned sh_n;
  __shared__ float sh_maxabs, sh_minnz, sh_maxnz;
  int tid = threadIdx.x;

  if (tid == 0) {
    float thr0 = compute_thr(st->sum0, st->sumsq0, st->n0);
    sh_thr[0] = thr0;
    finalize_group(thr0, st->maxabs0, st->n0, st->minnz0, st->maxnz0,
                   st->bmin0, st->bmax0, /*clampZero=*/false,
                   &sh_delta[0], &sh_zp[0], &sh_valid[0]);
    float thr1 = compute_thr(st->sum1, st->sumsq1, st->n1);
    sh_thr[1] = thr1;
    finalize_group(thr1, st->maxabs1, st->n1, st->minnz1, st->maxnz1,
                   st->bmin1, st->bmax1, /*clampZero=*/true,
                   &sh_delta[1], &sh_zp[1], &sh_valid[1]);
    sh_sum = st->sum2; sh_sumsq = st->sumsq2; sh_n = st->n2;
    sh_maxabs = st->maxabs2; sh_minnz = st->minnz2; sh_maxnz = st->maxnz2;
  }
  __syncthreads();
  unsigned c2 = st->count2; if (c2 > cap2) c2 = cap2;

  for (int i = 2; i < 10; ++i) {
    if (tid == 0) sh_thr[i] = compute_thr(sh_sum, sh_sumsq, sh_n);
    __syncthreads();
    float tp = sh_thr[i - 1], tc = sh_thr[i];
    Acc8 a; acc_init(a);
    for (unsigned j = tid; j < c2; j += 1024u) {
      float f = buf2[j];
      float ab = fabsf(f);
      if (ab > tp && ab <= tc) { a.bmin = fminf(a.bmin, f); a.bmax = fmaxf(a.bmax, f); }
      if (ab > tc) {
        a.cnt++; a.sum += (double)ab; a.sumsq += (double)ab * (double)ab;
        a.maxabs = fmaxf(a.maxabs, ab);
        a.minnz = fminf(a.minnz, f); a.maxnz = fmaxf(a.maxnz, f);
      }
    }
    if (acc_block_reduce<16>(a, s_part)) {
      finalize_group(tc, sh_maxabs, sh_n, sh_minnz, sh_maxnz, a.bmin, a.bmax,
                     /*clampZero=*/true, &sh_delta[i], &sh_zp[i], &sh_valid[i]);
      if (sh_n > 0u) {  // done-propagation: keep zeros once dead
        sh_sum = a.sum; sh_sumsq = a.sumsq; sh_n = a.cnt;
        sh_maxabs = a.maxabs; sh_minnz = a.minnz; sh_maxnz = a.maxnz;
      }
    }
    __syncthreads();
  }
  if (tid < 10) {
    st->thr[tid] = sh_thr[tid]; st->delta[tid] = sh_delta[tid];
    st->zp[tid] = sh_zp[tid];   st->valid[tid] = sh_valid[tid];
  }
}

// ---------------------------------------------------------------------------
// K5: pure band-0 stream (inliers are ~99%; k6 fixes outliers afterwards).
// Numerics per element identical to the old chain's band-0 path.
// ---------------------------------------------------------------------------
__device__ inline float dq0(float v, float d0, float z0) {
  float q = rintf(v / d0) + z0;          // IEEE divide + half-even round
  q = fminf(fmaxf(q, 0.0f), 255.0f);
  return (q - z0) * d0;
}

__global__ void __launch_bounds__(256) k5_dequant(const float* __restrict__ x, float* __restrict__ out,
                                                  long long n, const State* __restrict__ st) {
  float d0 = st->delta[0], z0 = st->zp[0];
  const f32x4* x4 = (const f32x4*)x;
  f32x4* o4 = (f32x4*)out;
  long long n4 = n >> 2;
  long long tid = (long long)blockIdx.x * NT + threadIdx.x;
  long long nthreads = (long long)gridDim.x * NT;
  long long step = nthreads * 8;
  long long nfull = (n4 / step) * step;
  for (long long i = (long long)blockIdx.x * (NT * 8) + threadIdx.x; i < nfull; i += step) {
    f32x4 v[8];
    #pragma unroll
    for (int u = 0; u < 8; ++u) v[u] = x4[i + u * NT];
    #pragma unroll
    for (int u = 0; u < 8; ++u) {
      f32x4 o;
      o.x = dq0(v[u].x, d0, z0);
      o.y = dq0(v[u].y, d0, z0);
      o.z = dq0(v[u].z, d0, z0);
      o.w = dq0(v[u].w, d0, z0);
      __builtin_nontemporal_store(o, &o4[i + u * NT]);
    }
  }
  for (long long i = nfull + tid; i < n4; i += nthreads) {
    f32x4 v = x4[i];
    f32x4 o;
    o.x = dq0(v.x, d0, z0); o.y = dq0(v.y, d0, z0);
    o.z = dq0(v.z, d0, z0); o.w = dq0(v.w, d0, z0);
    o4[i] = o;
  }
  for (long long i = (n4 << 2) + tid; i < n; i += nthreads) {
    out[i] = dq0(x[i], d0, z0);
  }
}

// ---------------------------------------------------------------------------
// K6: re-process the compacted outliers (~600K) with the full band chain and
// scatter into out. Runs AFTER k5 (overwrites its band-0 values).
// ---------------------------------------------------------------------------
__device__ inline float dq1(float v, const float* thr, const float* dl, const float* zp, const int* vld) {
  float ab = fabsf(v);
  float d = dl[0], z = zp[0];
  #pragma unroll
  for (int i = 1; i < 10; ++i) {
    bool band = (vld[i] != 0) && (ab > thr[i - 1]) && (ab <= thr[i]);
    d = band ? dl[i] : d;
    z = band ? zp[i] : z;
  }
  float q = rintf(v / d) + z;
  q = fminf(fmaxf(q, 0.0f), 255.0f);
  return (q - z) * d;
}

__global__ void __launch_bounds__(256) k6_outliers(const float2* __restrict__ buf1, unsigned cap1,
                                                   float* __restrict__ out, const State* __restrict__ st) {
  unsigned c1 = st->count1; if (c1 > cap1) c1 = cap1;
  float thr[10], dl[10], zp[10]; int vld[10];
  #pragma unroll
  for (int i = 0; i < 10; ++i) {
    thr[i] = st->thr[i]; dl[i] = st->delta[i]; zp[i] = st->zp[i]; vld[i] = st->valid[i];
  }
  unsigned stride = gridDim.x * blockDim.x;
  for (unsigned j = blockIdx.x * blockDim.x + threadIdx.x; j < c1; j += stride) {
    float2 rec = buf1[j];
    out[__float_as_uint(rec.y)] = dq1(rec.x, thr, dl, zp, vld);
  }
}

// ---------------------------------------------------------------------------
extern "C" void kernel_launch(void* const* d_in, const int* in_sizes, int n_in,
                              void* d_out, int out_size, void* d_ws, size_t ws_size,
                              hipStream_t stream) {
  const float* x = (const float*)d_in[0];
  float* out = (float*)d_out;
  long long n = (long long)in_sizes[0];

  // ws carve: State | partials1 | partials2 | buf2 (floats) | buf1 (pairs)
  char* p = (char*)d_ws;
  State* st = (State*)p;            p += 4096;
  Acc8* part1 = (Acc8*)p;           p += (size_t)NB * sizeof(Acc8);
  Acc8* part2 = (Acc8*)p;           p += (size_t)NB * sizeof(Acc8);
  size_t used = (size_t)(p - (char*)d_ws);
  used = (used + 255) & ~(size_t)255;
  size_t avail = ws_size > used ? ws_size - used : 0;
  size_t cap2_sz = avail / 8;
  if (cap2_sz > (size_t)(1u << 20) * 4) cap2_sz = (size_t)(1u << 20) * 4;
  unsigned cap2 = (unsigned)(cap2_sz / 4);
  float* buf2 = (float*)((char*)d_ws + used);
  float2* buf1 = (float2*)(buf2 + cap2);
  unsigned cap1 = (unsigned)((avail - (size_t)cap2 * 4) / 8);

  hipLaunchKernelGGL(k1_stats,    dim3(NB),  dim3(NT),   0, stream, x, n, part1);
  hipLaunchKernelGGL(k1r_reduce,  dim3(1),   dim3(1024), 0, stream, st, (const Acc8*)part1, NB);
  hipLaunchKernelGGL(k2_pass,     dim3(NB),  dim3(NT),   0, stream, x, n, st, buf1, cap1, part2);
  hipLaunchKernelGGL(k2r_reduce,  dim3(1),   dim3(1024), 0, stream, st, (const Acc8*)part2, NB);
  hipLaunchKernelGGL(k3_pass,     dim3(256), dim3(NT),   0, stream, st, (const float2*)buf1, cap1, buf2, cap2);
  hipLaunchKernelGGL(k4_finalize, dim3(1),   dim3(1024), 0, stream, st, (const float*)buf2, cap2);
  hipLaunchKernelGGL(k5_dequant,  dim3(NB),  dim3(NT),   0, stream, x, out, n, st);
  hipLaunchKernelGGL(k6_outliers, dim3(512), dim3(NT),   0, stream, (const float2*)buf1, cap1, out, st);
}